// Round 12
// baseline (8141.817 us; speedup 1.0000x reference)
//
#include <hip/hip_runtime.h>
#include <hip/hip_bf16.h>

// GroupedExperts: out[t] = (silu(x@w1[e]^T) * (x@w3[e]^T)) @ w2[e]^T
// E=8, T=16384, D=2048, H=5632; tokens pre-sorted by expert, even split.
//
// Round 12: 2 blocks/CU TLP with the PROVEN R6 fine-interleave schedule.
// One change from R11: LDS halved to 64KB (BK=32, 2-buf, no kk-slices) so
// two independent 8-wave blocks co-reside per CU (launch_bounds(512,4)).
// Block A's vmcnt/lgkm stalls are covered by block B's MFMA bursts
// (m114 wave-level MFMA/VALU co-issue mechanism). Per K32-tile: p0{rd 8;
// stage A(t+1); bar; lgkm0; 16 MFMA; bar} p1{rd 4; stage B(t+1);
// vmcnt(0); bar; lgkm0; 16 MFMA; bar}. Swizzle q^=(row>>1)&3 on 64B rows
// + per-lane-constant inverse staging source (R5/R6-proven, bit-same).
// Cluster mappings + fused w2 cvt + cvt_pre identical to R11 (best).

typedef __bf16 bf16x8 __attribute__((ext_vector_type(8)));
typedef float f32x4 __attribute__((ext_vector_type(4)));
typedef unsigned short u16x8 __attribute__((ext_vector_type(8)));

constexpr int E = 8;
constexpr int T = 16384;
constexpr int D = 2048;
constexpr int H = 5632;

#define DEV static __device__ __forceinline__

DEV unsigned short f2bf(float f) {
    unsigned u = __builtin_bit_cast(unsigned, f);
    u = (u + 0x7FFFu + ((u >> 16) & 1u)) >> 16;   // RNE
    return (unsigned short)u;
}

DEV void gload16(const void* g, void* l) {
    __builtin_amdgcn_global_load_lds(
        (const __attribute__((address_space(1))) void*)g,
        (__attribute__((address_space(3))) void*)l, 16, 0, 0);
}

DEV f32x4 mfma16(bf16x8 a, bf16x8 b, f32x4 c) {
    return __builtin_amdgcn_mfma_f32_16x16x32_bf16(a, b, c, 0, 0, 0);
}

DEV void cvt8(const float* src, unsigned short* dst) {
    float4 a = *(const float4*)src;
    float4 c = *(const float4*)(src + 4);
    u16x8 r;
    r[0] = f2bf(a.x); r[1] = f2bf(a.y); r[2] = f2bf(a.z); r[3] = f2bf(a.w);
    r[4] = f2bf(c.x); r[5] = f2bf(c.y); r[6] = f2bf(c.z); r[7] = f2bf(c.w);
    *(u16x8*)dst = r;
}

// ------- merged pre-GEMM converts: x (linear) + w1/w3 (interleave-16) -----
// w13b[e] row layout: rr = (h>>4)*32 + which*16 + (h&15); which 0=w1, 1=w3.
__global__ __launch_bounds__(256) void k_cvt_pre(
    const float* __restrict__ x, const float* __restrict__ w1,
    const float* __restrict__ w3, unsigned short* __restrict__ xb,
    unsigned short* __restrict__ w13b) {
    const int bid = blockIdx.x, tid = threadIdx.x;
    if (bid < 512) {
        const long n8 = (long)T * D / 8;
        for (long i = (long)bid * 256 + tid; i < n8; i += 512L * 256)
            cvt8(x + i * 8, xb + i * 8);
    } else {
        const int which = (bid < 1280) ? 0 : 1;
        const float* src = which ? w3 : w1;
        const long b0 = which ? 1280 : 512;
        const long n8 = (long)E * H * D / 8;
        for (long i = ((long)bid - b0) * 256 + tid; i < n8; i += 768L * 256) {
            int col8 = (int)(i & 255);          // D/8 = 256
            int rowi = (int)(i >> 8);           // e*H + h
            int e = rowi / H;
            int h = rowi - e * H;
            int rr = ((h >> 4) << 5) + (which << 4) + (h & 15);
            cvt8(src + i * 8,
                 w13b + ((size_t)e * (2 * H) + rr) * D + (size_t)col8 * 8);
        }
    }
}

// linear cvt (w2 fallback when ws too small for the fused path)
__global__ __launch_bounds__(256) void k_cvt(const float* __restrict__ in,
                                             unsigned short* __restrict__ out,
                                             long n8) {
    long i = (long)blockIdx.x * blockDim.x + threadIdx.x;
    long stride = (long)gridDim.x * blockDim.x;
    for (; i < n8; i += stride) cvt8(in + i * 8, out + i * 8);
}

// ---------------- expert lookup for a row tile ----------------------------
DEV int expert_of_row(const int* __restrict__ ntp, int row0) {
    int e = 0, s = 0;
    for (int i = 0; i < E; ++i) {
        int c = ntp[i];
        if (row0 < s + c) { e = i; break; }
        s += c;
    }
    return e;
}

// ---------------- 256x256 BK=32 2-phase GEMM core (64KB LDS) --------------
// 512 thr = 8 waves (2M x 4N); wave out 128x64 = acc[8][4] f32x4.
// LDS per operand: 2 buf x (256 rows x 32 el, 64B rows) = 32KB; total 64KB
// -> 2 blocks/CU. Swizzle: 16B quarter q of row r stored at q^((r>>1)&3).
// Per K32-tile: p0 rd{A m0-3, B n0-3} st A(t+1); bar; lgkm0; MFMA m0-3
//               p1 rd{A m4-7}         st B(t+1); vm0; bar; lgkm0; MFMA m4-7
template <int LD, int NT>
DEV void gemm_2p(const unsigned short* pa, const unsigned short* pb,
                 unsigned short* sA, unsigned short* sB, int tid,
                 f32x4 (&acc)[8][4]) {
    const int lane = tid & 63, wid = tid >> 6;
    const int wm = wid >> 2, wn = wid & 3;

    const int q8 = (((lane >> 4) ^ ((lane >> 1) & 3)) << 3);
    const int aoff = (wm * 128 + (lane & 15)) * 32 + q8;
    const int boff = (wn * 64 + (lane & 15)) * 32 + q8;

    char* lA = (char*)sA;
    char* lB = (char*)sB;
    const int dW = wid << 10;

    auto stA = [&](int t) {
        const unsigned short* g = pa + (size_t)t * 32;
        char* l = lA + ((t & 1) << 14) + dW;
        gload16(g, l);
        gload16(g + (size_t)128 * LD, l + 8192);
    };
    auto stB = [&](int t) {
        const unsigned short* g = pb + (size_t)t * 32;
        char* l = lB + ((t & 1) << 14) + dW;
        gload16(g, l);
        gload16(g + (size_t)128 * LD, l + 8192);
    };

    stA(0); stB(0);
    asm volatile("s_waitcnt vmcnt(0)" ::: "memory");
    __builtin_amdgcn_s_barrier();

#pragma unroll 1
    for (int t = 0; t < NT; ++t) {
        const int sb = (t & 1) << 13;             // buf base, ushorts
        const unsigned short* A = sA + sb + aoff;
        const unsigned short* B = sB + sb + boff;
        const bool more = (t + 1 < NT);
        bf16x8 a[4], b[4];

        // ===== p0: rd A m0-3 + B n0-3; stage A(t+1); MFMA m0-3 =====
#pragma unroll
        for (int i = 0; i < 4; ++i) a[i] = *(const bf16x8*)(A + i * 512);
#pragma unroll
        for (int i = 0; i < 4; ++i) b[i] = *(const bf16x8*)(B + i * 512);
        if (more) stA(t + 1);
        __builtin_amdgcn_s_barrier();
        asm volatile("s_waitcnt lgkmcnt(0)" ::: "memory");
        __builtin_amdgcn_sched_barrier(0);
        __builtin_amdgcn_s_setprio(1);
#pragma unroll
        for (int m = 0; m < 4; ++m)
#pragma unroll
            for (int n = 0; n < 4; ++n)
                acc[m][n] = mfma16(a[m], b[n], acc[m][n]);
        __builtin_amdgcn_s_setprio(0);
        __builtin_amdgcn_s_barrier();

        // ===== p1: rd A m4-7; stage B(t+1); vm0; MFMA m4-7 =====
#pragma unroll
        for (int i = 0; i < 4; ++i)
            a[i] = *(const bf16x8*)(A + 2048 + i * 512);
        if (more) {
            stB(t + 1);
            asm volatile("s_waitcnt vmcnt(0)" ::: "memory");
        }
        __builtin_amdgcn_s_barrier();
        asm volatile("s_waitcnt lgkmcnt(0)" ::: "memory");
        __builtin_amdgcn_sched_barrier(0);
        __builtin_amdgcn_s_setprio(1);
#pragma unroll
        for (int m = 0; m < 4; ++m)
#pragma unroll
            for (int n = 0; n < 4; ++n)
                acc[4 + m][n] = mfma16(a[m], b[n], acc[4 + m][n]);
        __builtin_amdgcn_s_setprio(0);
        __builtin_amdgcn_s_barrier();
    }
}

// ---------------- kernel 1: fused gate/up grouped GEMM + SwiGLU -----------
// A = xb (T x D), B = w13b[e] (2H x D interleave-16), h (T x H bf16).
// Optional fused w2 f32->bf16 convert (disjoint w2b region).
__global__ __launch_bounds__(512, 4) void k_gate_up(
    const unsigned short* __restrict__ xb,
    const unsigned short* __restrict__ w13b,
    const float* __restrict__ w2, unsigned short* __restrict__ w2b,
    const int* __restrict__ ntp, unsigned short* __restrict__ hbuf) {
    __shared__ unsigned short sA[2 * 8192];
    __shared__ unsigned short sB[2 * 8192];

    const int bid = blockIdx.x;
    const int tid = threadIdx.x;

    if (w2) {  // fused w2 convert: 32768 elems per block, then drain vmcnt
        const float* src = w2 + (size_t)bid * 32768;
        unsigned short* dst = w2b + (size_t)bid * 32768;
#pragma unroll
        for (int it = 0; it < 8; ++it) {
            int o = (it * 512 + tid) * 8;
            cvt8(src + o, dst + o);
        }
        asm volatile("s_waitcnt vmcnt(0)" ::: "memory");
    }

    // cluster mapping: XCD (bid&7) covers an 8tm x 4tn cluster window.
    const int tm = (bid & 7) * 8 + ((bid >> 3) & 7);
    const int tn = bid >> 6;  // 0..43

    const int row0 = tm << 8;
    const int e = expert_of_row(ntp, row0);
    const int lane = tid & 63, wid = tid >> 6;

    // staging sources: row = tid>>2, k-quarter = (tid&3)^((tid>>3)&3)
    const int sr = tid >> 2;
    const int sq = (tid & 3) ^ ((tid >> 3) & 3);
    const unsigned short* pa = xb + (size_t)(row0 + sr) * D + sq * 8;
    const unsigned short* pb = w13b + (size_t)e * (2 * H) * D +
                               (size_t)((tn << 8) + sr) * D + sq * 8;

    f32x4 acc[8][4] = {};
    gemm_2p<D, D / 32>(pa, pb, sA, sB, tid, acc);

    // Epilogue: ni pairs (0,1),(2,3) = (gate,up). C/D: col=lane&15,
    // row=(lane>>4)*4+j.
    const int wm = wid >> 2, wn = wid & 3;
    const int rbase = row0 + (wm << 7) + ((lane >> 4) << 2);
    const int cb = (((tn << 3) + (wn << 1)) << 4) + (lane & 15);
#pragma unroll
    for (int mi = 0; mi < 8; ++mi)
#pragma unroll
        for (int pi = 0; pi < 2; ++pi) {
            f32x4 g = acc[mi][2 * pi], u = acc[mi][2 * pi + 1];
            const int hcol = cb + (pi << 4);
#pragma unroll
            for (int j = 0; j < 4; ++j) {
                float gv = g[j];
                float hv = gv * u[j] / (1.f + __expf(-gv));
                hbuf[(size_t)(rbase + (mi << 4) + j) * H + hcol] = f2bf(hv);
            }
        }
}

// ---------------- kernel 2: down grouped GEMM -----------------------------
// A = h (T x H), B = w2b[e] (D x H), out (T x D f32). K = H = 5632.
// Expert-per-XCD cluster: XCD x owns tm in [8x,8x+8) x tn in [0,8).
__global__ __launch_bounds__(512, 4) void k_down(
    const unsigned short* __restrict__ hbuf,
    const unsigned short* __restrict__ w2b,
    const int* __restrict__ ntp,
    float* __restrict__ out) {
    __shared__ unsigned short sA[2 * 8192];
    __shared__ unsigned short sB[2 * 8192];

    const int bid = blockIdx.x;          // 512 blocks
    const int xcd = bid & 7;
    const int j = bid >> 3;              // 0..63
    const int tn = j & 7;
    const int tm = xcd * 8 + (j >> 3);   // 0..63, expert = xcd

    const int row0 = tm << 8;
    const int e = expert_of_row(ntp, row0);
    const int tid = threadIdx.x;
    const int lane = tid & 63, wid = tid >> 6;

    const int sr = tid >> 2;
    const int sq = (tid & 3) ^ ((tid >> 3) & 3);
    const unsigned short* pa = hbuf + (size_t)(row0 + sr) * H + sq * 8;
    const unsigned short* pb = w2b + (size_t)e * D * H +
                               (size_t)((tn << 8) + sr) * H + sq * 8;

    f32x4 acc[8][4] = {};
    gemm_2p<H, H / 32>(pa, pb, sA, sB, tid, acc);

    const int wm = wid >> 2, wn = wid & 3;
    const int rbase = row0 + (wm << 7) + ((lane >> 4) << 2);
    const int cb = (tn << 8) + (wn << 6) + (lane & 15);
#pragma unroll
    for (int mi = 0; mi < 8; ++mi)
#pragma unroll
        for (int ni = 0; ni < 4; ++ni) {
            f32x4 c = acc[mi][ni];
#pragma unroll
            for (int j2 = 0; j2 < 4; ++j2)
                out[(size_t)(rbase + (mi << 4) + j2) * D + cb + (ni << 4)] =
                    c[j2];
        }
}

extern "C" void kernel_launch(void* const* d_in, const int* in_sizes, int n_in,
                              void* d_out, int out_size, void* d_ws,
                              size_t ws_size, hipStream_t stream) {
    const float* x = (const float*)d_in[0];
    const float* w1 = (const float*)d_in[1];
    const float* w2 = (const float*)d_in[2];
    const float* w3 = (const float*)d_in[3];
    const int* ntp = (const int*)d_in[4];
    float* out = (float*)d_out;

    char* ws = (char*)d_ws;
    // ws layout (bytes):
    //   xb  : [0, 67108864)                       T*D*2
    //   w13b: [67108864, 436207616)               E*2H*D*2
    //   h   : [436207616, 620756992)              T*H*2
    //   w2b : [620756992, 805306368)  if ws fits  E*D*H*2 (else alias w13b)
    unsigned short* xb = (unsigned short*)(ws + 0);
    unsigned short* w13b = (unsigned short*)(ws + 67108864L);
    unsigned short* hbuf = (unsigned short*)(ws + 436207616L);
    const bool big = ws_size >= 805306368UL;
    unsigned short* w2b = big ? (unsigned short*)(ws + 620756992L) : w13b;

    k_cvt_pre<<<2048, 256, 0, stream>>>(x, w1, w3, xb, w13b);

    k_gate_up<<<(T / 256) * (2 * H / 256), 512, 0, stream>>>(
        xb, w13b, big ? w2 : nullptr, big ? w2b : nullptr, ntp, hbuf);

    if (!big)
        k_cvt<<<2048, 256, 0, stream>>>(w2, w2b, (long)E * D * H / 8);

    k_down<<<(T / 256) * (D / 256), 512, 0, stream>>>(hbuf, w2b, ntp, out);
}

// Round 13
// 1368.721 us; speedup vs baseline: 5.9485x; 5.9485x over previous
//
#include <hip/hip_runtime.h>
#include <hip/hip_bf16.h>

// GroupedExperts: out[t] = (silu(x@w1[e]^T) * (x@w3[e]^T)) @ w2[e]^T
// E=8, T=16384, D=2048, H=5632; tokens pre-sorted by expert, even split.
//
// Round 13: revert to R11 (best, 1393us). ONE bounded change: k_down uses
// gemm_4p2 = R6 core with 8 -> 2 barriers per K-tile (mid+end, each with
// counted vmcnt(4); hazard ledger verified incl. prologue and tails).
// Fewer lockstep points let waves drift -> cross-wave LDS||MFMA overlap.
// k_gate_up byte-identical to R11 (bounded risk A/B).

typedef __bf16 bf16x8 __attribute__((ext_vector_type(8)));
typedef float f32x4 __attribute__((ext_vector_type(4)));
typedef unsigned short u16x8 __attribute__((ext_vector_type(8)));

constexpr int E = 8;
constexpr int T = 16384;
constexpr int D = 2048;
constexpr int H = 5632;

#define DEV static __device__ __forceinline__

DEV unsigned short f2bf(float f) {
    unsigned u = __builtin_bit_cast(unsigned, f);
    u = (u + 0x7FFFu + ((u >> 16) & 1u)) >> 16;   // RNE
    return (unsigned short)u;
}

DEV void gload16(const void* g, void* l) {
    __builtin_amdgcn_global_load_lds(
        (const __attribute__((address_space(1))) void*)g,
        (__attribute__((address_space(3))) void*)l, 16, 0, 0);
}

DEV f32x4 mfma16(bf16x8 a, bf16x8 b, f32x4 c) {
    return __builtin_amdgcn_mfma_f32_16x16x32_bf16(a, b, c, 0, 0, 0);
}

DEV void cvt8(const float* src, unsigned short* dst) {
    float4 a = *(const float4*)src;
    float4 c = *(const float4*)(src + 4);
    u16x8 r;
    r[0] = f2bf(a.x); r[1] = f2bf(a.y); r[2] = f2bf(a.z); r[3] = f2bf(a.w);
    r[4] = f2bf(c.x); r[5] = f2bf(c.y); r[6] = f2bf(c.z); r[7] = f2bf(c.w);
    *(u16x8*)dst = r;
}

// ------- merged pre-GEMM converts: x (linear) + w1/w3 (interleave-16) -----
// w13b[e] row layout: rr = (h>>4)*32 + which*16 + (h&15); which 0=w1, 1=w3.
__global__ __launch_bounds__(256) void k_cvt_pre(
    const float* __restrict__ x, const float* __restrict__ w1,
    const float* __restrict__ w3, unsigned short* __restrict__ xb,
    unsigned short* __restrict__ w13b) {
    const int bid = blockIdx.x, tid = threadIdx.x;
    if (bid < 512) {
        const long n8 = (long)T * D / 8;
        for (long i = (long)bid * 256 + tid; i < n8; i += 512L * 256)
            cvt8(x + i * 8, xb + i * 8);
    } else {
        const int which = (bid < 1280) ? 0 : 1;
        const float* src = which ? w3 : w1;
        const long b0 = which ? 1280 : 512;
        const long n8 = (long)E * H * D / 8;
        for (long i = ((long)bid - b0) * 256 + tid; i < n8; i += 768L * 256) {
            int col8 = (int)(i & 255);          // D/8 = 256
            int rowi = (int)(i >> 8);           // e*H + h
            int e = rowi / H;
            int h = rowi - e * H;
            int rr = ((h >> 4) << 5) + (which << 4) + (h & 15);
            cvt8(src + i * 8,
                 w13b + ((size_t)e * (2 * H) + rr) * D + (size_t)col8 * 8);
        }
    }
}

// linear cvt (w2 fallback when ws too small for the fused path)
__global__ __launch_bounds__(256) void k_cvt(const float* __restrict__ in,
                                             unsigned short* __restrict__ out,
                                             long n8) {
    long i = (long)blockIdx.x * blockDim.x + threadIdx.x;
    long stride = (long)gridDim.x * blockDim.x;
    for (; i < n8; i += stride) cvt8(in + i * 8, out + i * 8);
}

// ---------------- expert lookup for a row tile ----------------------------
DEV int expert_of_row(const int* __restrict__ ntp, int row0) {
    int e = 0, s = 0;
    for (int i = 0; i < E; ++i) {
        int c = ntp[i];
        if (row0 < s + c) { e = i; break; }
        s += c;
    }
    return e;
}

// ---------------- 256x256 BK=64 4-phase GEMM core (R6 verbatim) -----------
// 512 thr = 8 waves (2M x 4N); wave out 128x64 = acc[8][4] f32x4.
// LDS per operand: 2 buf x 2 kk-slice x (256 rows x 32 el, 64B rows) = 64KB.
// Swizzle: 16B quarter q of row r stored at q ^ ((r>>1)&3).
template <int LD, int NT>
DEV void gemm_4p(const unsigned short* pa, const unsigned short* pb,
                 unsigned short* sA, unsigned short* sB, int tid,
                 f32x4 (&acc)[8][4]) {
    const int lane = tid & 63, wid = tid >> 6;
    const int wm = wid >> 2, wn = wid & 3;

    const int q8 = (((lane >> 4) ^ ((lane >> 1) & 3)) << 3);
    const int aoff = (wm * 128 + (lane & 15)) * 32 + q8;
    const int boff = (wn * 64 + (lane & 15)) * 32 + q8;

    char* lA = (char*)sA;
    char* lB = (char*)sB;
    const int dW = wid << 10;

    auto stA = [&](int t, int kk) {
        const unsigned short* g = pa + (size_t)t * 64 + kk * 32;
        char* l = lA + ((t & 1) << 15) + (kk << 14) + dW;
        gload16(g, l);
        gload16(g + (size_t)128 * LD, l + 8192);
    };
    auto stB = [&](int t, int kk) {
        const unsigned short* g = pb + (size_t)t * 64 + kk * 32;
        char* l = lB + ((t & 1) << 15) + (kk << 14) + dW;
        gload16(g, l);
        gload16(g + (size_t)128 * LD, l + 8192);
    };

    stA(0, 0); stB(0, 0); stA(0, 1); stB(0, 1);
    asm volatile("s_waitcnt vmcnt(4)" ::: "memory");
    __builtin_amdgcn_s_barrier();

#pragma unroll 1
    for (int t = 0; t < NT; ++t) {
        const int sb = (t & 1) << 14;
        const unsigned short* A0 = sA + sb + aoff;
        const unsigned short* B0 = sB + sb + boff;
        const unsigned short* A1 = A0 + 8192;
        const unsigned short* B1 = B0 + 8192;
        const bool more = (t + 1 < NT);
        bf16x8 a[4], b[4];

        // ===== p0 =====
#pragma unroll
        for (int i = 0; i < 4; ++i) a[i] = *(const bf16x8*)(A0 + i * 512);
#pragma unroll
        for (int i = 0; i < 4; ++i) b[i] = *(const bf16x8*)(B0 + i * 512);
        if (more) stA(t + 1, 0);
        __builtin_amdgcn_s_barrier();
        asm volatile("s_waitcnt lgkmcnt(0)" ::: "memory");
        __builtin_amdgcn_sched_barrier(0);
        __builtin_amdgcn_s_setprio(1);
#pragma unroll
        for (int m = 0; m < 4; ++m)
#pragma unroll
            for (int n = 0; n < 4; ++n)
                acc[m][n] = mfma16(a[m], b[n], acc[m][n]);
        __builtin_amdgcn_s_setprio(0);
        __builtin_amdgcn_s_barrier();

        // ===== p1 =====
#pragma unroll
        for (int i = 0; i < 4; ++i)
            a[i] = *(const bf16x8*)(A0 + 2048 + i * 512);
        if (more) {
            stB(t + 1, 0);
            asm volatile("s_waitcnt vmcnt(4)" ::: "memory");
        } else {
            asm volatile("s_waitcnt vmcnt(0)" ::: "memory");
        }
        __builtin_amdgcn_s_barrier();
        asm volatile("s_waitcnt lgkmcnt(0)" ::: "memory");
        __builtin_amdgcn_sched_barrier(0);
        __builtin_amdgcn_s_setprio(1);
#pragma unroll
        for (int m = 0; m < 4; ++m)
#pragma unroll
            for (int n = 0; n < 4; ++n)
                acc[4 + m][n] = mfma16(a[m], b[n], acc[4 + m][n]);
        __builtin_amdgcn_s_setprio(0);
        __builtin_amdgcn_s_barrier();

        // ===== p2 =====
#pragma unroll
        for (int i = 0; i < 4; ++i) a[i] = *(const bf16x8*)(A1 + i * 512);
#pragma unroll
        for (int i = 0; i < 4; ++i) b[i] = *(const bf16x8*)(B1 + i * 512);
        if (more) stA(t + 1, 1);
        __builtin_amdgcn_s_barrier();
        asm volatile("s_waitcnt lgkmcnt(0)" ::: "memory");
        __builtin_amdgcn_sched_barrier(0);
        __builtin_amdgcn_s_setprio(1);
#pragma unroll
        for (int m = 0; m < 4; ++m)
#pragma unroll
            for (int n = 0; n < 4; ++n)
                acc[m][n] = mfma16(a[m], b[n], acc[m][n]);
        __builtin_amdgcn_s_setprio(0);
        __builtin_amdgcn_s_barrier();

        // ===== p3 =====
#pragma unroll
        for (int i = 0; i < 4; ++i)
            a[i] = *(const bf16x8*)(A1 + 2048 + i * 512);
        if (more) {
            stB(t + 1, 1);
            asm volatile("s_waitcnt vmcnt(4)" ::: "memory");
        }
        __builtin_amdgcn_s_barrier();
        asm volatile("s_waitcnt lgkmcnt(0)" ::: "memory");
        __builtin_amdgcn_sched_barrier(0);
        __builtin_amdgcn_s_setprio(1);
#pragma unroll
        for (int m = 0; m < 4; ++m)
#pragma unroll
            for (int n = 0; n < 4; ++n)
                acc[4 + m][n] = mfma16(a[m], b[n], acc[4 + m][n]);
        __builtin_amdgcn_s_setprio(0);
        __builtin_amdgcn_s_barrier();
    }
}

// ---------------- variant: 2 barriers per K-tile (k_down A/B) -------------
// Same geometry/stages as gemm_4p. Barriers only at mid-tile and end-tile,
// each preceded by counted vmcnt. Ledger (steady state, per wave, stages
// issue p0:A0' p1:B0' p2:A1' p3:B1'):
//   entering tile t: outstanding = {A1(t),B1(t)} (4)
//   mid vmcnt(4): outstanding {A1(t),B1(t),A0(t+1),B0(t+1)}=8 -> retires
//     kk1(t) pair; mid barrier publishes -> p2/p3 reads safe
//   end vmcnt(4): retires kk0(t+1) pair; end barrier -> next tile p0 safe
// Tails: t=NT-1 mid uses vmcnt(0) (no new stages); end barrier skipped.
template <int LD, int NT>
DEV void gemm_4p2(const unsigned short* pa, const unsigned short* pb,
                  unsigned short* sA, unsigned short* sB, int tid,
                  f32x4 (&acc)[8][4]) {
    const int lane = tid & 63, wid = tid >> 6;
    const int wm = wid >> 2, wn = wid & 3;

    const int q8 = (((lane >> 4) ^ ((lane >> 1) & 3)) << 3);
    const int aoff = (wm * 128 + (lane & 15)) * 32 + q8;
    const int boff = (wn * 64 + (lane & 15)) * 32 + q8;

    char* lA = (char*)sA;
    char* lB = (char*)sB;
    const int dW = wid << 10;

    auto stA = [&](int t, int kk) {
        const unsigned short* g = pa + (size_t)t * 64 + kk * 32;
        char* l = lA + ((t & 1) << 15) + (kk << 14) + dW;
        gload16(g, l);
        gload16(g + (size_t)128 * LD, l + 8192);
    };
    auto stB = [&](int t, int kk) {
        const unsigned short* g = pb + (size_t)t * 64 + kk * 32;
        char* l = lB + ((t & 1) << 15) + (kk << 14) + dW;
        gload16(g, l);
        gload16(g + (size_t)128 * LD, l + 8192);
    };

    stA(0, 0); stB(0, 0); stA(0, 1); stB(0, 1);
    asm volatile("s_waitcnt vmcnt(4)" ::: "memory");  // retire kk0(0)
    __builtin_amdgcn_s_barrier();

#pragma unroll 1
    for (int t = 0; t < NT; ++t) {
        const int sb = (t & 1) << 14;
        const unsigned short* A0 = sA + sb + aoff;
        const unsigned short* B0 = sB + sb + boff;
        const unsigned short* A1 = A0 + 8192;
        const unsigned short* B1 = B0 + 8192;
        const bool more = (t + 1 < NT);
        bf16x8 a[4], b[4];

        // ===== half 0 (kk0) =====
#pragma unroll
        for (int i = 0; i < 4; ++i) a[i] = *(const bf16x8*)(A0 + i * 512);
#pragma unroll
        for (int i = 0; i < 4; ++i) b[i] = *(const bf16x8*)(B0 + i * 512);
        if (more) stA(t + 1, 0);
        asm volatile("s_waitcnt lgkmcnt(0)" ::: "memory");
        __builtin_amdgcn_sched_barrier(0);
        __builtin_amdgcn_s_setprio(1);
#pragma unroll
        for (int m = 0; m < 4; ++m)
#pragma unroll
            for (int n = 0; n < 4; ++n)
                acc[m][n] = mfma16(a[m], b[n], acc[m][n]);
        __builtin_amdgcn_s_setprio(0);

#pragma unroll
        for (int i = 0; i < 4; ++i)
            a[i] = *(const bf16x8*)(A0 + 2048 + i * 512);
        if (more) stB(t + 1, 0);
        asm volatile("s_waitcnt lgkmcnt(0)" ::: "memory");
        __builtin_amdgcn_sched_barrier(0);
        __builtin_amdgcn_s_setprio(1);
#pragma unroll
        for (int m = 0; m < 4; ++m)
#pragma unroll
            for (int n = 0; n < 4; ++n)
                acc[4 + m][n] = mfma16(a[m], b[n], acc[4 + m][n]);
        __builtin_amdgcn_s_setprio(0);

        if (more) asm volatile("s_waitcnt vmcnt(4)" ::: "memory");
        else      asm volatile("s_waitcnt vmcnt(0)" ::: "memory");
        __builtin_amdgcn_s_barrier();   // mid-tile: publish kk1(t)
        __builtin_amdgcn_sched_barrier(0);

        // ===== half 1 (kk1) =====
#pragma unroll
        for (int i = 0; i < 4; ++i) a[i] = *(const bf16x8*)(A1 + i * 512);
#pragma unroll
        for (int i = 0; i < 4; ++i) b[i] = *(const bf16x8*)(B1 + i * 512);
        if (more) stA(t + 1, 1);
        asm volatile("s_waitcnt lgkmcnt(0)" ::: "memory");
        __builtin_amdgcn_sched_barrier(0);
        __builtin_amdgcn_s_setprio(1);
#pragma unroll
        for (int m = 0; m < 4; ++m)
#pragma unroll
            for (int n = 0; n < 4; ++n)
                acc[m][n] = mfma16(a[m], b[n], acc[m][n]);
        __builtin_amdgcn_s_setprio(0);

#pragma unroll
        for (int i = 0; i < 4; ++i)
            a[i] = *(const bf16x8*)(A1 + 2048 + i * 512);
        if (more) stB(t + 1, 1);
        asm volatile("s_waitcnt lgkmcnt(0)" ::: "memory");
        __builtin_amdgcn_sched_barrier(0);
        __builtin_amdgcn_s_setprio(1);
#pragma unroll
        for (int m = 0; m < 4; ++m)
#pragma unroll
            for (int n = 0; n < 4; ++n)
                acc[4 + m][n] = mfma16(a[m], b[n], acc[4 + m][n]);
        __builtin_amdgcn_s_setprio(0);

        if (more) {
            asm volatile("s_waitcnt vmcnt(4)" ::: "memory");
            __builtin_amdgcn_s_barrier();   // end-tile: publish kk0(t+1)
            __builtin_amdgcn_sched_barrier(0);
        }
    }
}

// ---------------- kernel 1: fused gate/up grouped GEMM + SwiGLU -----------
// A = xb (T x D), B = w13b[e] (2H x D interleave-16), h (T x H bf16).
// Optional fused w2 f32->bf16 convert (disjoint w2b region, R4-proven).
__global__ __launch_bounds__(512, 2) void k_gate_up(
    const unsigned short* __restrict__ xb,
    const unsigned short* __restrict__ w13b,
    const float* __restrict__ w2, unsigned short* __restrict__ w2b,
    const int* __restrict__ ntp, unsigned short* __restrict__ hbuf) {
    __shared__ unsigned short sA[2 * 2 * 8192];
    __shared__ unsigned short sB[2 * 2 * 8192];

    const int bid = blockIdx.x;
    const int tid = threadIdx.x;

    if (w2) {  // fused w2 convert: 32768 elems per block, then drain vmcnt
        const float* src = w2 + (size_t)bid * 32768;
        unsigned short* dst = w2b + (size_t)bid * 32768;
#pragma unroll
        for (int it = 0; it < 8; ++it) {
            int o = (it * 512 + tid) * 8;
            cvt8(src + o, dst + o);
        }
        asm volatile("s_waitcnt vmcnt(0)" ::: "memory");
    }

    // cluster mapping: XCD (bid&7) covers an 8tm x 4tn cluster window.
    const int tm = (bid & 7) * 8 + ((bid >> 3) & 7);
    const int tn = bid >> 6;  // 0..43

    const int row0 = tm << 8;
    const int e = expert_of_row(ntp, row0);
    const int lane = tid & 63, wid = tid >> 6;

    // staging sources: row = tid>>2, k-quarter = (tid&3)^((tid>>3)&3)
    const int sr = tid >> 2;
    const int sq = (tid & 3) ^ ((tid >> 3) & 3);
    const unsigned short* pa = xb + (size_t)(row0 + sr) * D + sq * 8;
    const unsigned short* pb = w13b + (size_t)e * (2 * H) * D +
                               (size_t)((tn << 8) + sr) * D + sq * 8;

    f32x4 acc[8][4] = {};
    gemm_4p<D, D / 64>(pa, pb, sA, sB, tid, acc);

    // Epilogue: ni pairs (0,1),(2,3) = (gate,up). C/D: col=lane&15,
    // row=(lane>>4)*4+j.
    const int wm = wid >> 2, wn = wid & 3;
    const int rbase = row0 + (wm << 7) + ((lane >> 4) << 2);
    const int cb = (((tn << 3) + (wn << 1)) << 4) + (lane & 15);
#pragma unroll
    for (int mi = 0; mi < 8; ++mi)
#pragma unroll
        for (int pi = 0; pi < 2; ++pi) {
            f32x4 g = acc[mi][2 * pi], u = acc[mi][2 * pi + 1];
            const int hcol = cb + (pi << 4);
#pragma unroll
            for (int j = 0; j < 4; ++j) {
                float gv = g[j];
                float hv = gv * u[j] / (1.f + __expf(-gv));
                hbuf[(size_t)(rbase + (mi << 4) + j) * H + hcol] = f2bf(hv);
            }
        }
}

// ---------------- kernel 2: down grouped GEMM -----------------------------
// A = h (T x H), B = w2b[e] (D x H), out (T x D f32). K = H = 5632.
// Expert-per-XCD cluster (R11). Uses the 2-barrier gemm_4p2 variant (A/B).
__global__ __launch_bounds__(512, 2) void k_down(
    const unsigned short* __restrict__ hbuf,
    const unsigned short* __restrict__ w2b,
    const int* __restrict__ ntp,
    float* __restrict__ out) {
    __shared__ unsigned short sA[2 * 2 * 8192];
    __shared__ unsigned short sB[2 * 2 * 8192];

    const int bid = blockIdx.x;          // 512 blocks
    const int xcd = bid & 7;
    const int j = bid >> 3;              // 0..63
    const int tn = j & 7;
    const int tm = xcd * 8 + (j >> 3);   // 0..63, expert = xcd

    const int row0 = tm << 8;
    const int e = expert_of_row(ntp, row0);
    const int tid = threadIdx.x;
    const int lane = tid & 63, wid = tid >> 6;

    const int sr = tid >> 2;
    const int sq = (tid & 3) ^ ((tid >> 3) & 3);
    const unsigned short* pa = hbuf + (size_t)(row0 + sr) * H + sq * 8;
    const unsigned short* pb = w2b + (size_t)e * D * H +
                               (size_t)((tn << 8) + sr) * H + sq * 8;

    f32x4 acc[8][4] = {};
    gemm_4p2<H, H / 64>(pa, pb, sA, sB, tid, acc);

    const int wm = wid >> 2, wn = wid & 3;
    const int rbase = row0 + (wm << 7) + ((lane >> 4) << 2);
    const int cb = (tn << 8) + (wn << 6) + (lane & 15);
#pragma unroll
    for (int mi = 0; mi < 8; ++mi)
#pragma unroll
        for (int ni = 0; ni < 4; ++ni) {
            f32x4 c = acc[mi][ni];
#pragma unroll
            for (int j2 = 0; j2 < 4; ++j2)
                out[(size_t)(rbase + (mi << 4) + j2) * D + cb + (ni << 4)] =
                    c[j2];
        }
}

extern "C" void kernel_launch(void* const* d_in, const int* in_sizes, int n_in,
                              void* d_out, int out_size, void* d_ws,
                              size_t ws_size, hipStream_t stream) {
    const float* x = (const float*)d_in[0];
    const float* w1 = (const float*)d_in[1];
    const float* w2 = (const float*)d_in[2];
    const float* w3 = (const float*)d_in[3];
    const int* ntp = (const int*)d_in[4];
    float* out = (float*)d_out;

    char* ws = (char*)d_ws;
    // ws layout (bytes):
    //   xb  : [0, 67108864)                       T*D*2
    //   w13b: [67108864, 436207616)               E*2H*D*2
    //   h   : [436207616, 620756992)              T*H*2
    //   w2b : [620756992, 805306368)  if ws fits  E*D*H*2 (else alias w13b)
    unsigned short* xb = (unsigned short*)(ws + 0);
    unsigned short* w13b = (unsigned short*)(ws + 67108864L);
    unsigned short* hbuf = (unsigned short*)(ws + 436207616L);
    const bool big = ws_size >= 805306368UL;
    unsigned short* w2b = big ? (unsigned short*)(ws + 620756992L) : w13b;

    k_cvt_pre<<<2048, 256, 0, stream>>>(x, w1, w3, xb, w13b);

    k_gate_up<<<(T / 256) * (2 * H / 256), 512, 0, stream>>>(
        xb, w13b, big ? w2 : nullptr, big ? w2b : nullptr, ntp, hbuf);

    if (!big)
        k_cvt<<<2048, 256, 0, stream>>>(w2, w2b, (long)E * D * H / 8);

    k_down<<<(T / 256) * (D / 256), 512, 0, stream>>>(hbuf, w2b, ntp, out);
}

// Round 14
// 1349.385 us; speedup vs baseline: 6.0337x; 1.0143x over previous
//
#include <hip/hip_runtime.h>
#include <hip/hip_bf16.h>

// GroupedExperts: out[t] = (silu(x@w1[e]^T) * (x@w3[e]^T)) @ w2[e]^T
// E=8, T=16384, D=2048, H=5632; tokens pre-sorted by expert, even split.
//
// Round 14: port the R13-validated 2-barrier schedule (gemm_4p2) to BOTH
// GEMMs. R13 proved it on k_down (+8%, correct): mid+end barrier per
// K-tile, each preceded by counted vmcnt(4); waves de-phase within the
// block so ds_read bursts overlap MFMA bursts across waves (m114).
// Unused 8-barrier core deleted (rule #19). Everything else = R13/R11:
// cluster mappings, fused w2 cvt, merged pre-convert, swizzle pair.

typedef __bf16 bf16x8 __attribute__((ext_vector_type(8)));
typedef float f32x4 __attribute__((ext_vector_type(4)));
typedef unsigned short u16x8 __attribute__((ext_vector_type(8)));

constexpr int E = 8;
constexpr int T = 16384;
constexpr int D = 2048;
constexpr int H = 5632;

#define DEV static __device__ __forceinline__

DEV unsigned short f2bf(float f) {
    unsigned u = __builtin_bit_cast(unsigned, f);
    u = (u + 0x7FFFu + ((u >> 16) & 1u)) >> 16;   // RNE
    return (unsigned short)u;
}

DEV void gload16(const void* g, void* l) {
    __builtin_amdgcn_global_load_lds(
        (const __attribute__((address_space(1))) void*)g,
        (__attribute__((address_space(3))) void*)l, 16, 0, 0);
}

DEV f32x4 mfma16(bf16x8 a, bf16x8 b, f32x4 c) {
    return __builtin_amdgcn_mfma_f32_16x16x32_bf16(a, b, c, 0, 0, 0);
}

DEV void cvt8(const float* src, unsigned short* dst) {
    float4 a = *(const float4*)src;
    float4 c = *(const float4*)(src + 4);
    u16x8 r;
    r[0] = f2bf(a.x); r[1] = f2bf(a.y); r[2] = f2bf(a.z); r[3] = f2bf(a.w);
    r[4] = f2bf(c.x); r[5] = f2bf(c.y); r[6] = f2bf(c.z); r[7] = f2bf(c.w);
    *(u16x8*)dst = r;
}

// ------- merged pre-GEMM converts: x (linear) + w1/w3 (interleave-16) -----
// w13b[e] row layout: rr = (h>>4)*32 + which*16 + (h&15); which 0=w1, 1=w3.
__global__ __launch_bounds__(256) void k_cvt_pre(
    const float* __restrict__ x, const float* __restrict__ w1,
    const float* __restrict__ w3, unsigned short* __restrict__ xb,
    unsigned short* __restrict__ w13b) {
    const int bid = blockIdx.x, tid = threadIdx.x;
    if (bid < 512) {
        const long n8 = (long)T * D / 8;
        for (long i = (long)bid * 256 + tid; i < n8; i += 512L * 256)
            cvt8(x + i * 8, xb + i * 8);
    } else {
        const int which = (bid < 1280) ? 0 : 1;
        const float* src = which ? w3 : w1;
        const long b0 = which ? 1280 : 512;
        const long n8 = (long)E * H * D / 8;
        for (long i = ((long)bid - b0) * 256 + tid; i < n8; i += 768L * 256) {
            int col8 = (int)(i & 255);          // D/8 = 256
            int rowi = (int)(i >> 8);           // e*H + h
            int e = rowi / H;
            int h = rowi - e * H;
            int rr = ((h >> 4) << 5) + (which << 4) + (h & 15);
            cvt8(src + i * 8,
                 w13b + ((size_t)e * (2 * H) + rr) * D + (size_t)col8 * 8);
        }
    }
}

// linear cvt (w2 fallback when ws too small for the fused path)
__global__ __launch_bounds__(256) void k_cvt(const float* __restrict__ in,
                                             unsigned short* __restrict__ out,
                                             long n8) {
    long i = (long)blockIdx.x * blockDim.x + threadIdx.x;
    long stride = (long)gridDim.x * blockDim.x;
    for (; i < n8; i += stride) cvt8(in + i * 8, out + i * 8);
}

// ---------------- expert lookup for a row tile ----------------------------
DEV int expert_of_row(const int* __restrict__ ntp, int row0) {
    int e = 0, s = 0;
    for (int i = 0; i < E; ++i) {
        int c = ntp[i];
        if (row0 < s + c) { e = i; break; }
        s += c;
    }
    return e;
}

// ------- 256x256 BK=64 GEMM core, 2 barriers per K-tile (R13-proven) ------
// 512 thr = 8 waves (2M x 4N); wave out 128x64 = acc[8][4] f32x4.
// LDS per operand: 2 buf x 2 kk-slice x (256 rows x 32 el, 64B rows) = 64KB.
// Swizzle: 16B quarter q of row r stored at q ^ ((r>>1)&3).
// Stages per tile: h0 issues A0(t+1), B0(t+1); h1 issues A1(t+1), B1(t+1).
// Ledger (steady state, per wave):
//   entering tile t: outstanding = {A1(t),B1(t)} (4 loads)
//   mid vmcnt(4): retires kk1(t) pair; mid barrier publishes -> h1 reads ok
//   end vmcnt(4): retires kk0(t+1) pair; end barrier -> next h0 reads ok
// Tails: last tile mid uses vmcnt(0); end barrier skipped.
template <int LD, int NT>
DEV void gemm_4p2(const unsigned short* pa, const unsigned short* pb,
                  unsigned short* sA, unsigned short* sB, int tid,
                  f32x4 (&acc)[8][4]) {
    const int lane = tid & 63, wid = tid >> 6;
    const int wm = wid >> 2, wn = wid & 3;

    const int q8 = (((lane >> 4) ^ ((lane >> 1) & 3)) << 3);
    const int aoff = (wm * 128 + (lane & 15)) * 32 + q8;
    const int boff = (wn * 64 + (lane & 15)) * 32 + q8;

    char* lA = (char*)sA;
    char* lB = (char*)sB;
    const int dW = wid << 10;

    auto stA = [&](int t, int kk) {
        const unsigned short* g = pa + (size_t)t * 64 + kk * 32;
        char* l = lA + ((t & 1) << 15) + (kk << 14) + dW;
        gload16(g, l);
        gload16(g + (size_t)128 * LD, l + 8192);
    };
    auto stB = [&](int t, int kk) {
        const unsigned short* g = pb + (size_t)t * 64 + kk * 32;
        char* l = lB + ((t & 1) << 15) + (kk << 14) + dW;
        gload16(g, l);
        gload16(g + (size_t)128 * LD, l + 8192);
    };

    stA(0, 0); stB(0, 0); stA(0, 1); stB(0, 1);
    asm volatile("s_waitcnt vmcnt(4)" ::: "memory");  // retire kk0(0)
    __builtin_amdgcn_s_barrier();

#pragma unroll 1
    for (int t = 0; t < NT; ++t) {
        const int sb = (t & 1) << 14;
        const unsigned short* A0 = sA + sb + aoff;
        const unsigned short* B0 = sB + sb + boff;
        const unsigned short* A1 = A0 + 8192;
        const unsigned short* B1 = B0 + 8192;
        const bool more = (t + 1 < NT);
        bf16x8 a[4], b[4];

        // ===== half 0 (kk0) =====
#pragma unroll
        for (int i = 0; i < 4; ++i) a[i] = *(const bf16x8*)(A0 + i * 512);
#pragma unroll
        for (int i = 0; i < 4; ++i) b[i] = *(const bf16x8*)(B0 + i * 512);
        if (more) stA(t + 1, 0);
        asm volatile("s_waitcnt lgkmcnt(0)" ::: "memory");
        __builtin_amdgcn_sched_barrier(0);
        __builtin_amdgcn_s_setprio(1);
#pragma unroll
        for (int m = 0; m < 4; ++m)
#pragma unroll
            for (int n = 0; n < 4; ++n)
                acc[m][n] = mfma16(a[m], b[n], acc[m][n]);
        __builtin_amdgcn_s_setprio(0);

#pragma unroll
        for (int i = 0; i < 4; ++i)
            a[i] = *(const bf16x8*)(A0 + 2048 + i * 512);
        if (more) stB(t + 1, 0);
        asm volatile("s_waitcnt lgkmcnt(0)" ::: "memory");
        __builtin_amdgcn_sched_barrier(0);
        __builtin_amdgcn_s_setprio(1);
#pragma unroll
        for (int m = 0; m < 4; ++m)
#pragma unroll
            for (int n = 0; n < 4; ++n)
                acc[4 + m][n] = mfma16(a[m], b[n], acc[4 + m][n]);
        __builtin_amdgcn_s_setprio(0);

        if (more) asm volatile("s_waitcnt vmcnt(4)" ::: "memory");
        else      asm volatile("s_waitcnt vmcnt(0)" ::: "memory");
        __builtin_amdgcn_s_barrier();   // mid-tile: publish kk1(t)
        __builtin_amdgcn_sched_barrier(0);

        // ===== half 1 (kk1) =====
#pragma unroll
        for (int i = 0; i < 4; ++i) a[i] = *(const bf16x8*)(A1 + i * 512);
#pragma unroll
        for (int i = 0; i < 4; ++i) b[i] = *(const bf16x8*)(B1 + i * 512);
        if (more) stA(t + 1, 1);
        asm volatile("s_waitcnt lgkmcnt(0)" ::: "memory");
        __builtin_amdgcn_sched_barrier(0);
        __builtin_amdgcn_s_setprio(1);
#pragma unroll
        for (int m = 0; m < 4; ++m)
#pragma unroll
            for (int n = 0; n < 4; ++n)
                acc[m][n] = mfma16(a[m], b[n], acc[m][n]);
        __builtin_amdgcn_s_setprio(0);

#pragma unroll
        for (int i = 0; i < 4; ++i)
            a[i] = *(const bf16x8*)(A1 + 2048 + i * 512);
        if (more) stB(t + 1, 1);
        asm volatile("s_waitcnt lgkmcnt(0)" ::: "memory");
        __builtin_amdgcn_sched_barrier(0);
        __builtin_amdgcn_s_setprio(1);
#pragma unroll
        for (int m = 0; m < 4; ++m)
#pragma unroll
            for (int n = 0; n < 4; ++n)
                acc[4 + m][n] = mfma16(a[m], b[n], acc[4 + m][n]);
        __builtin_amdgcn_s_setprio(0);

        if (more) {
            asm volatile("s_waitcnt vmcnt(4)" ::: "memory");
            __builtin_amdgcn_s_barrier();   // end-tile: publish kk0(t+1)
            __builtin_amdgcn_sched_barrier(0);
        }
    }
}

// ---------------- kernel 1: fused gate/up grouped GEMM + SwiGLU -----------
// A = xb (T x D), B = w13b[e] (2H x D interleave-16), h (T x H bf16).
// Optional fused w2 f32->bf16 convert (disjoint w2b region, R4-proven).
__global__ __launch_bounds__(512, 2) void k_gate_up(
    const unsigned short* __restrict__ xb,
    const unsigned short* __restrict__ w13b,
    const float* __restrict__ w2, unsigned short* __restrict__ w2b,
    const int* __restrict__ ntp, unsigned short* __restrict__ hbuf) {
    __shared__ unsigned short sA[2 * 2 * 8192];
    __shared__ unsigned short sB[2 * 2 * 8192];

    const int bid = blockIdx.x;
    const int tid = threadIdx.x;

    if (w2) {  // fused w2 convert: 32768 elems per block, then drain vmcnt
        const float* src = w2 + (size_t)bid * 32768;
        unsigned short* dst = w2b + (size_t)bid * 32768;
#pragma unroll
        for (int it = 0; it < 8; ++it) {
            int o = (it * 512 + tid) * 8;
            cvt8(src + o, dst + o);
        }
        asm volatile("s_waitcnt vmcnt(0)" ::: "memory");
    }

    // cluster mapping: XCD (bid&7) covers an 8tm x 4tn cluster window.
    const int tm = (bid & 7) * 8 + ((bid >> 3) & 7);
    const int tn = bid >> 6;  // 0..43

    const int row0 = tm << 8;
    const int e = expert_of_row(ntp, row0);
    const int lane = tid & 63, wid = tid >> 6;

    // staging sources: row = tid>>2, k-quarter = (tid&3)^((tid>>3)&3)
    const int sr = tid >> 2;
    const int sq = (tid & 3) ^ ((tid >> 3) & 3);
    const unsigned short* pa = xb + (size_t)(row0 + sr) * D + sq * 8;
    const unsigned short* pb = w13b + (size_t)e * (2 * H) * D +
                               (size_t)((tn << 8) + sr) * D + sq * 8;

    f32x4 acc[8][4] = {};
    gemm_4p2<D, D / 64>(pa, pb, sA, sB, tid, acc);

    // Epilogue: ni pairs (0,1),(2,3) = (gate,up). C/D: col=lane&15,
    // row=(lane>>4)*4+j.
    const int wm = wid >> 2, wn = wid & 3;
    const int rbase = row0 + (wm << 7) + ((lane >> 4) << 2);
    const int cb = (((tn << 3) + (wn << 1)) << 4) + (lane & 15);
#pragma unroll
    for (int mi = 0; mi < 8; ++mi)
#pragma unroll
        for (int pi = 0; pi < 2; ++pi) {
            f32x4 g = acc[mi][2 * pi], u = acc[mi][2 * pi + 1];
            const int hcol = cb + (pi << 4);
#pragma unroll
            for (int j = 0; j < 4; ++j) {
                float gv = g[j];
                float hv = gv * u[j] / (1.f + __expf(-gv));
                hbuf[(size_t)(rbase + (mi << 4) + j) * H + hcol] = f2bf(hv);
            }
        }
}

// ---------------- kernel 2: down grouped GEMM -----------------------------
// A = h (T x H), B = w2b[e] (D x H), out (T x D f32). K = H = 5632.
// Expert-per-XCD cluster (R11): XCD x owns tm in [8x,8x+8) x tn in [0,8).
__global__ __launch_bounds__(512, 2) void k_down(
    const unsigned short* __restrict__ hbuf,
    const unsigned short* __restrict__ w2b,
    const int* __restrict__ ntp,
    float* __restrict__ out) {
    __shared__ unsigned short sA[2 * 2 * 8192];
    __shared__ unsigned short sB[2 * 2 * 8192];

    const int bid = blockIdx.x;          // 512 blocks
    const int xcd = bid & 7;
    const int j = bid >> 3;              // 0..63
    const int tn = j & 7;
    const int tm = xcd * 8 + (j >> 3);   // 0..63, expert = xcd

    const int row0 = tm << 8;
    const int e = expert_of_row(ntp, row0);
    const int tid = threadIdx.x;
    const int lane = tid & 63, wid = tid >> 6;

    const int sr = tid >> 2;
    const int sq = (tid & 3) ^ ((tid >> 3) & 3);
    const unsigned short* pa = hbuf + (size_t)(row0 + sr) * H + sq * 8;
    const unsigned short* pb = w2b + (size_t)e * D * H +
                               (size_t)((tn << 8) + sr) * H + sq * 8;

    f32x4 acc[8][4] = {};
    gemm_4p2<H, H / 64>(pa, pb, sA, sB, tid, acc);

    const int wm = wid >> 2, wn = wid & 3;
    const int rbase = row0 + (wm << 7) + ((lane >> 4) << 2);
    const int cb = (tn << 8) + (wn << 6) + (lane & 15);
#pragma unroll
    for (int mi = 0; mi < 8; ++mi)
#pragma unroll
        for (int ni = 0; ni < 4; ++ni) {
            f32x4 c = acc[mi][ni];
#pragma unroll
            for (int j2 = 0; j2 < 4; ++j2)
                out[(size_t)(rbase + (mi << 4) + j2) * D + cb + (ni << 4)] =
                    c[j2];
        }
}

extern "C" void kernel_launch(void* const* d_in, const int* in_sizes, int n_in,
                              void* d_out, int out_size, void* d_ws,
                              size_t ws_size, hipStream_t stream) {
    const float* x = (const float*)d_in[0];
    const float* w1 = (const float*)d_in[1];
    const float* w2 = (const float*)d_in[2];
    const float* w3 = (const float*)d_in[3];
    const int* ntp = (const int*)d_in[4];
    float* out = (float*)d_out;

    char* ws = (char*)d_ws;
    // ws layout (bytes):
    //   xb  : [0, 67108864)                       T*D*2
    //   w13b: [67108864, 436207616)               E*2H*D*2
    //   h   : [436207616, 620756992)              T*H*2
    //   w2b : [620756992, 805306368)  if ws fits  E*D*H*2 (else alias w13b)
    unsigned short* xb = (unsigned short*)(ws + 0);
    unsigned short* w13b = (unsigned short*)(ws + 67108864L);
    unsigned short* hbuf = (unsigned short*)(ws + 436207616L);
    const bool big = ws_size >= 805306368UL;
    unsigned short* w2b = big ? (unsigned short*)(ws + 620756992L) : w13b;

    k_cvt_pre<<<2048, 256, 0, stream>>>(x, w1, w3, xb, w13b);

    k_gate_up<<<(T / 256) * (2 * H / 256), 512, 0, stream>>>(
        xb, w13b, big ? w2 : nullptr, big ? w2b : nullptr, ntp, hbuf);

    if (!big)
        k_cvt<<<2048, 256, 0, stream>>>(w2, w2b, (long)E * D * H / 8);

    k_down<<<(T / 256) * (D / 256), 512, 0, stream>>>(hbuf, w2b, ntp, out);
}